// Round 4
// baseline (423.762 us; speedup 1.0000x reference)
//
#include <hip/hip_runtime.h>
#include <stdint.h>

// EfficientSelfAttention on MI355X (gfx950). External I/O is FP32 (per the
// reference dtypes); internals are bf16 for MFMA. B=4, T=4096, D=1024, H=8,
// Dh=128. Scratch in module __device__ globals (no d_ws dependence).
// Pipeline:
//   1. transpose+cast Wq/Wk/Wv -> bf16 [N][K]
//   2. LayerNorm x (fp32) -> xn (bf16)
//   3. gemm_kv: xn @ Wk^T / Wv^T, epilogue exp-select/mask, LDS-transposed
//        store -> ekT[b][d][t], vvT[b][l][t]  (bf16)
//   4. zrow: Z[b][d] = sum_t ekT
//   5. gemm_att (K-split 8): attp[c][bh][d][l] = sum_t ekT*vvT (fp32)
//   6. attnorm: reduce chunks, /Z, store attT[bh][l][d] bf16
//   7. gemm_qy: q-GEMM + exp + Zq rowsum + qs@attT^T + fp32 residual out

typedef unsigned short u16;
typedef __attribute__((ext_vector_type(8))) short bf16x8;
typedef __attribute__((ext_vector_type(4))) float f32x4;

// ------------------------------------------------------- device workspace
__device__ u16 g_WT[3][1024 * 1024];   // 6 MiB: WqT, WkT, WvT (bf16)
__device__ u16 g_xn[16777216];         // 32 MiB
__device__ u16 g_ekT[16777216];        // 32 MiB  [b][d][t]
__device__ u16 g_vvT[16777216];        // 32 MiB  [b][l][t]
__device__ float g_attp[4194304];      // 16 MiB  [kc*32+bh][d*128+l]
__device__ u16 g_attT[524288];         // 1 MiB   [bh][l*128+d]
__device__ float g_Z[4096];            //         [b*1024+d]

__device__ __forceinline__ float b2f(u16 u) {
  union { unsigned int i; float f; } c;
  c.i = ((unsigned int)u) << 16;
  return c.f;
}
__device__ __forceinline__ u16 f2b(float f) {
  union { float f; unsigned int i; } c;
  c.f = f;
  unsigned int r = c.i + 0x7fffu + ((c.i >> 16) & 1u);
  return (u16)(r >> 16);
}

__device__ __forceinline__ void gload16(const void* g, void* l) {
  __builtin_amdgcn_global_load_lds(
      reinterpret_cast<const __attribute__((address_space(1))) uint32_t*>(
          reinterpret_cast<uintptr_t>(g)),
      reinterpret_cast<__attribute__((address_space(3))) uint32_t*>(
          reinterpret_cast<uintptr_t>(l)),
      16, 0, 0);
}

// Stage 128x32 bf16 tile (row stride `stride` elems) into 8KB LDS [128][32].
__device__ __forceinline__ void stage128x32(const u16* g, int stride, char* lds,
                                            int wave, int lane) {
  const int r = wave * 32 + (lane >> 2);
  const int cb = (lane & 3) * 16;
  const char* gp = (const char*)g;
  gload16(gp + (size_t)r * stride * 2 + cb, lds + wave * 2048);
  gload16(gp + (size_t)(r + 16) * stride * 2 + cb, lds + wave * 2048 + 1024);
}

// A/B fragment from [128][32] LDS tile: row `row`, k = (lane>>4)*8 .. +7
__device__ __forceinline__ bf16x8 frag_ld(const char* lds, int row, int lane) {
  return *(const bf16x8*)(lds + row * 64 + ((lane >> 4) * 16));
}

// ---------------------------------------------------------------- LayerNorm
__global__ __launch_bounds__(256) void ln_kernel(const float* __restrict__ x,
                                                 const float* __restrict__ gamma,
                                                 const float* __restrict__ beta) {
  const int row = blockIdx.x;
  const int tid = threadIdx.x;
  const int wave = tid >> 6, lane = tid & 63;
  const float* xr = x + (size_t)row * 1024;
  float4 u = ((const float4*)xr)[tid];
  float v0 = u.x, v1 = u.y, v2 = u.z, v3 = u.w;
  float s = v0 + v1 + v2 + v3;
  float s2 = v0 * v0 + v1 * v1 + v2 * v2 + v3 * v3;
#pragma unroll
  for (int off = 32; off > 0; off >>= 1) {
    s += __shfl_down(s, off);
    s2 += __shfl_down(s2, off);
  }
  __shared__ float ls[4], ls2[4];
  if (lane == 0) { ls[wave] = s; ls2[wave] = s2; }
  __syncthreads();
  s = ls[0] + ls[1] + ls[2] + ls[3];
  s2 = ls2[0] + ls2[1] + ls2[2] + ls2[3];
  const float mu = s * (1.0f / 1024.0f);
  const float var = fmaxf(s2 * (1.0f / 1024.0f) - mu * mu, 0.0f);
  const float rstd = rsqrtf(var + 1e-5f);
  float4 g4 = ((const float4*)gamma)[tid];
  float4 be = ((const float4*)beta)[tid];
  ushort4 o;
  o.x = f2b((v0 - mu) * rstd * g4.x + be.x);
  o.y = f2b((v1 - mu) * rstd * g4.y + be.y);
  o.z = f2b((v2 - mu) * rstd * g4.z + be.z);
  o.w = f2b((v3 - mu) * rstd * g4.w + be.w);
  *(ushort4*)(g_xn + (size_t)row * 1024 + tid * 4) = o;
}

// ------------------------------------- weight transpose+cast (1Kx1K, fp32->bf16)
__global__ __launch_bounds__(256) void transpose_kernel(const float* __restrict__ src,
                                                        int which) {
  __shared__ u16 tile[32][33];
  u16* dst = g_WT[which];
  const int tx = threadIdx.x & 31;
  const int ty = threadIdx.x >> 5;
  const int c0 = blockIdx.x * 32, r0 = blockIdx.y * 32;
#pragma unroll
  for (int i = 0; i < 4; i++)
    tile[ty + i * 8][tx] = f2b(src[(size_t)(r0 + ty + i * 8) * 1024 + c0 + tx]);
  __syncthreads();
#pragma unroll
  for (int i = 0; i < 4; i++)
    dst[(size_t)(c0 + ty + i * 8) * 1024 + r0 + tx] = tile[tx][ty + i * 8];
}

// --------------------------------------------------------------- K/V GEMM
// z=0: ekT[b][d][t] = (m>0.5) ? exp(xn@Wk^T + bk) : 0
// z=1: vvT[b][l][t] = (xn@Wv^T + bv) * m
__global__ __launch_bounds__(256) void gemm_kv(const float* __restrict__ bk,
                                               const float* __restrict__ bv,
                                               const float* __restrict__ mask) {
  __shared__ __align__(16) char As[8192];
  __shared__ __align__(16) char Bs[8192];
  __shared__ __align__(16) u16 tT[128 * 136];  // [feature][token], padded
  const int tid = threadIdx.x, wave = tid >> 6, lane = tid & 63;
  const int n0 = blockIdx.x * 128;  // feature block
  const int m0 = blockIdx.y * 128;  // global token block (b*4096+t)
  const int z = blockIdx.z;
  const u16* wt = z ? g_WT[2] : g_WT[1];
  const float* bias = z ? bv : bk;
  u16* outT = z ? g_vvT : g_ekT;
  const int b = m0 >> 12;
  const int t0 = m0 & 4095;
  const int wm = wave & 1, wn = wave >> 1;

  f32x4 zero = {0.f, 0.f, 0.f, 0.f};
  f32x4 acc[4][4];
#pragma unroll
  for (int i = 0; i < 4; i++)
#pragma unroll
    for (int j = 0; j < 4; j++) acc[i][j] = zero;

  for (int k0 = 0; k0 < 1024; k0 += 32) {
    __syncthreads();
    stage128x32(g_xn + (size_t)m0 * 1024 + k0, 1024, As, wave, lane);
    stage128x32(wt + (size_t)n0 * 1024 + k0, 1024, Bs, wave, lane);
    __syncthreads();
    bf16x8 af[4], bfr[4];
#pragma unroll
    for (int i = 0; i < 4; i++) af[i] = frag_ld(As, wm * 64 + i * 16 + (lane & 15), lane);
#pragma unroll
    for (int j = 0; j < 4; j++) bfr[j] = frag_ld(Bs, wn * 64 + j * 16 + (lane & 15), lane);
#pragma unroll
    for (int i = 0; i < 4; i++)
#pragma unroll
      for (int j = 0; j < 4; j++)
        acc[i][j] = __builtin_amdgcn_mfma_f32_16x16x32_bf16(af[i], bfr[j], acc[i][j], 0, 0, 0);
  }

#pragma unroll
  for (int i = 0; i < 4; i++)
#pragma unroll
    for (int r = 0; r < 4; r++) {
      const int rowl = wm * 64 + i * 16 + (lane >> 4) * 4 + r;  // local token
      const float mv = mask[m0 + rowl];
#pragma unroll
      for (int j = 0; j < 4; j++) {
        const int coll = wn * 64 + j * 16 + (lane & 15);  // local feature
        const float a = acc[i][j][r] + bias[n0 + coll];
        float o;
        if (z)
          o = a * mv;
        else
          o = (mv > 0.5f) ? __expf(fminf(a, 30.0f)) : 0.0f;
        tT[coll * 136 + rowl] = f2b(o);
      }
    }
  __syncthreads();
  const size_t gbase = (size_t)b * (1024 * 4096) + (size_t)n0 * 4096 + t0;
#pragma unroll
  for (int u = 0; u < 8; u++) {
    const int v = u * 256 + tid;
    const int c = v >> 4, rb = (v & 15) * 8;
    uint4 val = *(const uint4*)&tT[c * 136 + rb];
    *(uint4*)(outT + gbase + (size_t)c * 4096 + rb) = val;
  }
}

// --------------------------------------------------- Z[b][d] = sum_t ekT
__global__ __launch_bounds__(256) void zrow_kernel() {
  const int tid = threadIdx.x, wave = tid >> 6, lane = tid & 63;
  const int d = blockIdx.x * 4 + wave;
  const int b = blockIdx.y;
  const u16* p = g_ekT + (size_t)b * (1024 * 4096) + (size_t)d * 4096;
  float s = 0.f;
#pragma unroll
  for (int pass = 0; pass < 8; pass++) {
    uint4 w4 = *(const uint4*)(p + pass * 512 + lane * 8);
    unsigned int w[4] = {w4.x, w4.y, w4.z, w4.w};
#pragma unroll
    for (int q = 0; q < 4; q++) {
      s += b2f((u16)(w[q] & 0xffff));
      s += b2f((u16)(w[q] >> 16));
    }
  }
#pragma unroll
  for (int m = 1; m < 64; m <<= 1) s += __shfl_xor(s, m);
  if (lane == 0) g_Z[b * 1024 + d] = s;
}

// ------------------------------------------------------------- att GEMM
// attp[kc][bh][d][l] = sum_{t in chunk kc} ekT[b][h*128+d][t]*vvT[b][h*128+l][t]
__global__ __launch_bounds__(256) void gemm_att() {
  __shared__ __align__(16) char As[8192];
  __shared__ __align__(16) char Bs[8192];
  const int tid = threadIdx.x, wave = tid >> 6, lane = tid & 63;
  const int kc = blockIdx.x;  // 0..7
  const int bh = blockIdx.y;  // 0..31
  const int b = bh >> 3, h = bh & 7;
  const size_t base = (size_t)b * (1024 * 4096) + (size_t)(h * 128) * 4096;
  const int wm = wave & 1, wn = wave >> 1;

  f32x4 zero = {0.f, 0.f, 0.f, 0.f};
  f32x4 acc[4][4];
#pragma unroll
  for (int i = 0; i < 4; i++)
#pragma unroll
    for (int j = 0; j < 4; j++) acc[i][j] = zero;

  for (int kt = 0; kt < 512; kt += 32) {
    const int k0 = kc * 512 + kt;
    __syncthreads();
    stage128x32(g_ekT + base + k0, 4096, As, wave, lane);
    stage128x32(g_vvT + base + k0, 4096, Bs, wave, lane);
    __syncthreads();
    bf16x8 af[4], bfr[4];
#pragma unroll
    for (int i = 0; i < 4; i++) af[i] = frag_ld(As, wm * 64 + i * 16 + (lane & 15), lane);
#pragma unroll
    for (int j = 0; j < 4; j++) bfr[j] = frag_ld(Bs, wn * 64 + j * 16 + (lane & 15), lane);
#pragma unroll
    for (int i = 0; i < 4; i++)
#pragma unroll
      for (int j = 0; j < 4; j++)
        acc[i][j] = __builtin_amdgcn_mfma_f32_16x16x32_bf16(af[i], bfr[j], acc[i][j], 0, 0, 0);
  }

  float* op = g_attp + ((size_t)(kc * 32 + bh)) * 16384;
#pragma unroll
  for (int i = 0; i < 4; i++)
#pragma unroll
    for (int r = 0; r < 4; r++) {
      const int row = wm * 64 + i * 16 + (lane >> 4) * 4 + r;
#pragma unroll
      for (int j = 0; j < 4; j++) {
        const int col = wn * 64 + j * 16 + (lane & 15);
        op[row * 128 + col] = acc[i][j][r];
      }
    }
}

// ------------------------------------- reduce partials, /Z, store attT[bh][l][d]
__global__ __launch_bounds__(256) void attnorm_kernel() {
  const int bh = blockIdx.x;
  const int b = bh >> 3, h = bh & 7;
  const int tid = threadIdx.x;
  __shared__ float Zl[128];
  if (tid < 128) Zl[tid] = fmaxf(g_Z[b * 1024 + h * 128 + tid], 1e-30f);
  __syncthreads();
  for (int i = tid; i < 16384; i += 256) {
    const int d = i >> 7, l = i & 127;
    float s = 0.f;
#pragma unroll
    for (int c = 0; c < 8; c++) s += g_attp[((size_t)(c * 32 + bh)) * 16384 + i];
    g_attT[(size_t)bh * 16384 + l * 128 + d] = f2b(s / Zl[d]);
  }
}

// ---------------------------------------------------------- fused q + y
__global__ __launch_bounds__(256) void gemm_qy(const float* __restrict__ bq,
                                               const float* __restrict__ x,
                                               float* __restrict__ out) {
  __shared__ __align__(16) char As[8192];
  __shared__ __align__(16) char Bs[8192];
  __shared__ __align__(16) u16 qs[128 * 136];  // [token][feature] padded
  __shared__ float zqp[2][128];
  const int tid = threadIdx.x, wave = tid >> 6, lane = tid & 63;
  const int h = blockIdx.x;          // 0..7
  const int m0 = blockIdx.y * 128;   // global token block
  const int b = m0 >> 12;
  const int bh = b * 8 + h;
  const int wm = wave & 1, wn = wave >> 1;

  f32x4 zero = {0.f, 0.f, 0.f, 0.f};
  f32x4 acc[4][4];
#pragma unroll
  for (int i = 0; i < 4; i++)
#pragma unroll
    for (int j = 0; j < 4; j++) acc[i][j] = zero;

  // phase 1: q = xn @ WqT[head rows]
  for (int k0 = 0; k0 < 1024; k0 += 32) {
    __syncthreads();
    stage128x32(g_xn + (size_t)m0 * 1024 + k0, 1024, As, wave, lane);
    stage128x32(g_WT[0] + (size_t)(h * 128) * 1024 + k0, 1024, Bs, wave, lane);
    __syncthreads();
    bf16x8 af[4], bfr[4];
#pragma unroll
    for (int i = 0; i < 4; i++) af[i] = frag_ld(As, wm * 64 + i * 16 + (lane & 15), lane);
#pragma unroll
    for (int j = 0; j < 4; j++) bfr[j] = frag_ld(Bs, wn * 64 + j * 16 + (lane & 15), lane);
#pragma unroll
    for (int i = 0; i < 4; i++)
#pragma unroll
      for (int j = 0; j < 4; j++)
        acc[i][j] = __builtin_amdgcn_mfma_f32_16x16x32_bf16(af[i], bfr[j], acc[i][j], 0, 0, 0);
  }

  // epilogue 1: exp (clamped), store to qs, row-sum into zqp
#pragma unroll
  for (int i = 0; i < 4; i++)
#pragma unroll
    for (int r = 0; r < 4; r++) {
      const int rowl = wm * 64 + i * 16 + (lane >> 4) * 4 + r;
      float rs = 0.f;
#pragma unroll
      for (int j = 0; j < 4; j++) {
        const int coll = wn * 64 + j * 16 + (lane & 15);
        const float e = __expf(fminf(acc[i][j][r] + bq[h * 128 + coll], 30.0f));
        qs[rowl * 136 + coll] = f2b(e);
        rs += e;
      }
      rs += __shfl_xor(rs, 1);
      rs += __shfl_xor(rs, 2);
      rs += __shfl_xor(rs, 4);
      rs += __shfl_xor(rs, 8);
      if ((lane & 15) == 0) zqp[wn][rowl] = rs;
    }
  __syncthreads();

  // phase 2: y = qs @ attT[bh]^T  (K = 128)
  f32x4 acc2[4][4];
#pragma unroll
  for (int i = 0; i < 4; i++)
#pragma unroll
    for (int j = 0; j < 4; j++) acc2[i][j] = zero;

  for (int k0 = 0; k0 < 128; k0 += 32) {
    __syncthreads();
    stage128x32(g_attT + (size_t)bh * 16384 + k0, 128, Bs, wave, lane);
    __syncthreads();
    bf16x8 af[4], bfr[4];
#pragma unroll
    for (int i = 0; i < 4; i++)
      af[i] = *(const bf16x8*)&qs[(wm * 64 + i * 16 + (lane & 15)) * 136 + k0 + (lane >> 4) * 8];
#pragma unroll
    for (int j = 0; j < 4; j++) bfr[j] = frag_ld(Bs, wn * 64 + j * 16 + (lane & 15), lane);
#pragma unroll
    for (int i = 0; i < 4; i++)
#pragma unroll
      for (int j = 0; j < 4; j++)
        acc2[i][j] = __builtin_amdgcn_mfma_f32_16x16x32_bf16(af[i], bfr[j], acc2[i][j], 0, 0, 0);
  }

  // epilogue 2: out = x + y / Zq  (fp32)
#pragma unroll
  for (int i = 0; i < 4; i++)
#pragma unroll
    for (int r = 0; r < 4; r++) {
      const int rowl = wm * 64 + i * 16 + (lane >> 4) * 4 + r;
      const float zq = fmaxf(zqp[0][rowl] + zqp[1][rowl], 1e-30f);
      const size_t n = (size_t)m0 + rowl;
#pragma unroll
      for (int j = 0; j < 4; j++) {
        const int coll = wn * 64 + j * 16 + (lane & 15);
        const size_t idx = n * 1024 + h * 128 + coll;
        out[idx] = x[idx] + acc2[i][j][r] / zq;
      }
    }
}

// ----------------------------------------------------------------- launch
extern "C" void kernel_launch(void* const* d_in, const int* in_sizes, int n_in,
                              void* d_out, int out_size, void* d_ws, size_t ws_size,
                              hipStream_t stream) {
  const float* x = (const float*)d_in[0];
  const float* mask = (const float*)d_in[1];
  const float* Wq = (const float*)d_in[2];
  const float* bq = (const float*)d_in[3];
  const float* Wk = (const float*)d_in[4];
  const float* bk = (const float*)d_in[5];
  const float* Wv = (const float*)d_in[6];
  const float* bv = (const float*)d_in[7];
  const float* gamma = (const float*)d_in[8];
  const float* beta = (const float*)d_in[9];
  float* out = (float*)d_out;
  (void)d_ws; (void)ws_size;

  transpose_kernel<<<dim3(32, 32), 256, 0, stream>>>(Wq, 0);
  transpose_kernel<<<dim3(32, 32), 256, 0, stream>>>(Wk, 1);
  transpose_kernel<<<dim3(32, 32), 256, 0, stream>>>(Wv, 2);
  ln_kernel<<<dim3(16384), 256, 0, stream>>>(x, gamma, beta);
  gemm_kv<<<dim3(8, 128, 2), 256, 0, stream>>>(bk, bv, mask);
  zrow_kernel<<<dim3(256, 4), 256, 0, stream>>>();
  gemm_att<<<dim3(8, 32), 256, 0, stream>>>();
  attnorm_kernel<<<dim3(32), 256, 0, stream>>>();
  gemm_qy<<<dim3(8, 128), 256, 0, stream>>>(bq, x, out);
}

// Round 5
// 402.605 us; speedup vs baseline: 1.0525x; 1.0525x over previous
//
#include <hip/hip_runtime.h>
#include <stdint.h>

// EfficientSelfAttention on MI355X (gfx950). External I/O FP32; internals bf16
// MFMA. B=4, T=4096, D=1024, H=8, Dh=128. Scratch in __device__ globals.
// R5: gemm_kv LDS union (tT aliases As/Bs -> 4 blocks/CU), gemm_att 16 chunks,
// attnorm split 8x, merged weight transposes.

typedef unsigned short u16;
typedef __attribute__((ext_vector_type(8))) short bf16x8;
typedef __attribute__((ext_vector_type(4))) float f32x4;

// ------------------------------------------------------- device workspace
__device__ u16 g_WT[3][1024 * 1024];   // 6 MiB: WqT, WkT, WvT (bf16)
__device__ u16 g_xn[16777216];         // 32 MiB
__device__ u16 g_ekT[16777216];        // 32 MiB  [b][d][t]
__device__ u16 g_vvT[16777216];        // 32 MiB  [b][l][t]
__device__ float g_attp[8388608];      // 32 MiB  [kc*32+bh][d*128+l], 16 chunks
__device__ u16 g_attT[524288];         // 1 MiB   [bh][l*128+d]
__device__ float g_Z[4096];            //         [b*1024+d]

__device__ __forceinline__ float b2f(u16 u) {
  union { unsigned int i; float f; } c;
  c.i = ((unsigned int)u) << 16;
  return c.f;
}
__device__ __forceinline__ u16 f2b(float f) {
  union { float f; unsigned int i; } c;
  c.f = f;
  unsigned int r = c.i + 0x7fffu + ((c.i >> 16) & 1u);
  return (u16)(r >> 16);
}

__device__ __forceinline__ void gload16(const void* g, void* l) {
  __builtin_amdgcn_global_load_lds(
      reinterpret_cast<const __attribute__((address_space(1))) uint32_t*>(
          reinterpret_cast<uintptr_t>(g)),
      reinterpret_cast<__attribute__((address_space(3))) uint32_t*>(
          reinterpret_cast<uintptr_t>(l)),
      16, 0, 0);
}

// Stage 128x32 bf16 tile (row stride `stride` elems) into 8KB LDS [128][32].
__device__ __forceinline__ void stage128x32(const u16* g, int stride, char* lds,
                                            int wave, int lane) {
  const int r = wave * 32 + (lane >> 2);
  const int cb = (lane & 3) * 16;
  const char* gp = (const char*)g;
  gload16(gp + (size_t)r * stride * 2 + cb, lds + wave * 2048);
  gload16(gp + (size_t)(r + 16) * stride * 2 + cb, lds + wave * 2048 + 1024);
}

// A/B fragment from [128][32] LDS tile: row `row`, k = (lane>>4)*8 .. +7
__device__ __forceinline__ bf16x8 frag_ld(const char* lds, int row, int lane) {
  return *(const bf16x8*)(lds + row * 64 + ((lane >> 4) * 16));
}

// ---------------------------------------------------------------- LayerNorm
__global__ __launch_bounds__(256) void ln_kernel(const float* __restrict__ x,
                                                 const float* __restrict__ gamma,
                                                 const float* __restrict__ beta) {
  const int row = blockIdx.x;
  const int tid = threadIdx.x;
  const int wave = tid >> 6, lane = tid & 63;
  const float* xr = x + (size_t)row * 1024;
  float4 u = ((const float4*)xr)[tid];
  float v0 = u.x, v1 = u.y, v2 = u.z, v3 = u.w;
  float s = v0 + v1 + v2 + v3;
  float s2 = v0 * v0 + v1 * v1 + v2 * v2 + v3 * v3;
#pragma unroll
  for (int off = 32; off > 0; off >>= 1) {
    s += __shfl_down(s, off);
    s2 += __shfl_down(s2, off);
  }
  __shared__ float ls[4], ls2[4];
  if (lane == 0) { ls[wave] = s; ls2[wave] = s2; }
  __syncthreads();
  s = ls[0] + ls[1] + ls[2] + ls[3];
  s2 = ls2[0] + ls2[1] + ls2[2] + ls2[3];
  const float mu = s * (1.0f / 1024.0f);
  const float var = fmaxf(s2 * (1.0f / 1024.0f) - mu * mu, 0.0f);
  const float rstd = rsqrtf(var + 1e-5f);
  float4 g4 = ((const float4*)gamma)[tid];
  float4 be = ((const float4*)beta)[tid];
  ushort4 o;
  o.x = f2b((v0 - mu) * rstd * g4.x + be.x);
  o.y = f2b((v1 - mu) * rstd * g4.y + be.y);
  o.z = f2b((v2 - mu) * rstd * g4.z + be.z);
  o.w = f2b((v3 - mu) * rstd * g4.w + be.w);
  *(ushort4*)(g_xn + (size_t)row * 1024 + tid * 4) = o;
}

// -------------------- weight transpose+cast (1Kx1K, fp32->bf16), z = which W
__global__ __launch_bounds__(256) void transpose_kernel(const float* __restrict__ wq,
                                                        const float* __restrict__ wk,
                                                        const float* __restrict__ wv) {
  __shared__ u16 tile[32][33];
  const int which = blockIdx.z;
  const float* src = (which == 0) ? wq : (which == 1) ? wk : wv;
  u16* dst = g_WT[which];
  const int tx = threadIdx.x & 31;
  const int ty = threadIdx.x >> 5;
  const int c0 = blockIdx.x * 32, r0 = blockIdx.y * 32;
#pragma unroll
  for (int i = 0; i < 4; i++)
    tile[ty + i * 8][tx] = f2b(src[(size_t)(r0 + ty + i * 8) * 1024 + c0 + tx]);
  __syncthreads();
#pragma unroll
  for (int i = 0; i < 4; i++)
    dst[(size_t)(c0 + ty + i * 8) * 1024 + r0 + tx] = tile[tx][ty + i * 8];
}

// --------------------------------------------------------------- K/V GEMM
// z=0: ekT[b][d][t] = (m>0.5) ? exp(xn@Wk^T + bk) : 0
// z=1: vvT[b][l][t] = (xn@Wv^T + bv) * m
// LDS: tT (34816 B) aliases As+Bs (dead after K-loop) -> 4 blocks/CU.
__global__ __launch_bounds__(256) void gemm_kv(const float* __restrict__ bk,
                                               const float* __restrict__ bv,
                                               const float* __restrict__ mask) {
  __shared__ __align__(16) char smem[34816];
  char* As = smem;
  char* Bs = smem + 8192;
  u16* tT = (u16*)smem;  // [feature][token] 128x136, written AFTER K-loop
  const int tid = threadIdx.x, wave = tid >> 6, lane = tid & 63;
  const int n0 = blockIdx.x * 128;  // feature block
  const int m0 = blockIdx.y * 128;  // global token block (b*4096+t)
  const int z = blockIdx.z;
  const u16* wt = z ? g_WT[2] : g_WT[1];
  const float* bias = z ? bv : bk;
  u16* outT = z ? g_vvT : g_ekT;
  const int b = m0 >> 12;
  const int t0 = m0 & 4095;
  const int wm = wave & 1, wn = wave >> 1;

  f32x4 zero = {0.f, 0.f, 0.f, 0.f};
  f32x4 acc[4][4];
#pragma unroll
  for (int i = 0; i < 4; i++)
#pragma unroll
    for (int j = 0; j < 4; j++) acc[i][j] = zero;

  for (int k0 = 0; k0 < 1024; k0 += 32) {
    __syncthreads();
    stage128x32(g_xn + (size_t)m0 * 1024 + k0, 1024, As, wave, lane);
    stage128x32(wt + (size_t)n0 * 1024 + k0, 1024, Bs, wave, lane);
    __syncthreads();
    bf16x8 af[4], bfr[4];
#pragma unroll
    for (int i = 0; i < 4; i++) af[i] = frag_ld(As, wm * 64 + i * 16 + (lane & 15), lane);
#pragma unroll
    for (int j = 0; j < 4; j++) bfr[j] = frag_ld(Bs, wn * 64 + j * 16 + (lane & 15), lane);
#pragma unroll
    for (int i = 0; i < 4; i++)
#pragma unroll
      for (int j = 0; j < 4; j++)
        acc[i][j] = __builtin_amdgcn_mfma_f32_16x16x32_bf16(af[i], bfr[j], acc[i][j], 0, 0, 0);
  }
  __syncthreads();  // all waves done reading As/Bs before tT overwrites them

#pragma unroll
  for (int i = 0; i < 4; i++)
#pragma unroll
    for (int r = 0; r < 4; r++) {
      const int rowl = wm * 64 + i * 16 + (lane >> 4) * 4 + r;  // local token
      const float mv = mask[m0 + rowl];
#pragma unroll
      for (int j = 0; j < 4; j++) {
        const int coll = wn * 64 + j * 16 + (lane & 15);  // local feature
        const float a = acc[i][j][r] + bias[n0 + coll];
        float o;
        if (z)
          o = a * mv;
        else
          o = (mv > 0.5f) ? __expf(fminf(a, 30.0f)) : 0.0f;
        tT[coll * 136 + rowl] = f2b(o);
      }
    }
  __syncthreads();
  const size_t gbase = (size_t)b * (1024 * 4096) + (size_t)n0 * 4096 + t0;
#pragma unroll
  for (int u = 0; u < 8; u++) {
    const int v = u * 256 + tid;
    const int c = v >> 4, rb = (v & 15) * 8;
    uint4 val = *(const uint4*)&tT[c * 136 + rb];
    *(uint4*)(outT + gbase + (size_t)c * 4096 + rb) = val;
  }
}

// --------------------------------------------------- Z[b][d] = sum_t ekT
__global__ __launch_bounds__(256) void zrow_kernel() {
  const int tid = threadIdx.x, wave = tid >> 6, lane = tid & 63;
  const int d = blockIdx.x * 4 + wave;
  const int b = blockIdx.y;
  const u16* p = g_ekT + (size_t)b * (1024 * 4096) + (size_t)d * 4096;
  float s = 0.f;
#pragma unroll
  for (int pass = 0; pass < 8; pass++) {
    uint4 w4 = *(const uint4*)(p + pass * 512 + lane * 8);
    unsigned int w[4] = {w4.x, w4.y, w4.z, w4.w};
#pragma unroll
    for (int q = 0; q < 4; q++) {
      s += b2f((u16)(w[q] & 0xffff));
      s += b2f((u16)(w[q] >> 16));
    }
  }
#pragma unroll
  for (int m = 1; m < 64; m <<= 1) s += __shfl_xor(s, m);
  if (lane == 0) g_Z[b * 1024 + d] = s;
}

// ------------------------------------------------------------- att GEMM
// attp[kc][bh][d][l] = sum_{t in 256-chunk kc} ekT[b][h*128+d][t]*vvT[b][h*128+l][t]
__global__ __launch_bounds__(256) void gemm_att() {
  __shared__ __align__(16) char As[8192];
  __shared__ __align__(16) char Bs[8192];
  const int tid = threadIdx.x, wave = tid >> 6, lane = tid & 63;
  const int kc = blockIdx.x;  // 0..15
  const int bh = blockIdx.y;  // 0..31
  const int b = bh >> 3, h = bh & 7;
  const size_t base = (size_t)b * (1024 * 4096) + (size_t)(h * 128) * 4096;
  const int wm = wave & 1, wn = wave >> 1;

  f32x4 zero = {0.f, 0.f, 0.f, 0.f};
  f32x4 acc[4][4];
#pragma unroll
  for (int i = 0; i < 4; i++)
#pragma unroll
    for (int j = 0; j < 4; j++) acc[i][j] = zero;

  for (int kt = 0; kt < 256; kt += 32) {
    const int k0 = kc * 256 + kt;
    __syncthreads();
    stage128x32(g_ekT + base + k0, 4096, As, wave, lane);
    stage128x32(g_vvT + base + k0, 4096, Bs, wave, lane);
    __syncthreads();
    bf16x8 af[4], bfr[4];
#pragma unroll
    for (int i = 0; i < 4; i++) af[i] = frag_ld(As, wm * 64 + i * 16 + (lane & 15), lane);
#pragma unroll
    for (int j = 0; j < 4; j++) bfr[j] = frag_ld(Bs, wn * 64 + j * 16 + (lane & 15), lane);
#pragma unroll
    for (int i = 0; i < 4; i++)
#pragma unroll
      for (int j = 0; j < 4; j++)
        acc[i][j] = __builtin_amdgcn_mfma_f32_16x16x32_bf16(af[i], bfr[j], acc[i][j], 0, 0, 0);
  }

  float* op = g_attp + ((size_t)(kc * 32 + bh)) * 16384;
#pragma unroll
  for (int i = 0; i < 4; i++)
#pragma unroll
    for (int r = 0; r < 4; r++) {
      const int row = wm * 64 + i * 16 + (lane >> 4) * 4 + r;
#pragma unroll
      for (int j = 0; j < 4; j++) {
        const int col = wn * 64 + j * 16 + (lane & 15);
        op[row * 128 + col] = acc[i][j][r];
      }
    }
}

// ------------------------------------- reduce partials, /Z, store attT[bh][l][d]
__global__ __launch_bounds__(256) void attnorm_kernel() {
  const int bh = blockIdx.x;
  const int b = bh >> 3, h = bh & 7;
  const int tid = threadIdx.x;
  __shared__ float Zl[128];
  if (tid < 128) Zl[tid] = fmaxf(g_Z[b * 1024 + h * 128 + tid], 1e-30f);
  __syncthreads();
  const int i0 = blockIdx.y * 2048;
  for (int i = i0 + tid; i < i0 + 2048; i += 256) {
    const int d = i >> 7, l = i & 127;
    float s = 0.f;
#pragma unroll
    for (int c = 0; c < 16; c++) s += g_attp[((size_t)(c * 32 + bh)) * 16384 + i];
    g_attT[(size_t)bh * 16384 + l * 128 + d] = f2b(s / Zl[d]);
  }
}

// ---------------------------------------------------------- fused q + y
__global__ __launch_bounds__(256) void gemm_qy(const float* __restrict__ bq,
                                               const float* __restrict__ x,
                                               float* __restrict__ out) {
  __shared__ __align__(16) char As[8192];
  __shared__ __align__(16) char Bs[8192];
  __shared__ __align__(16) u16 qs[128 * 136];  // [token][feature] padded
  __shared__ float zqp[2][128];
  const int tid = threadIdx.x, wave = tid >> 6, lane = tid & 63;
  const int h = blockIdx.x;          // 0..7
  const int m0 = blockIdx.y * 128;   // global token block
  const int b = m0 >> 12;
  const int bh = b * 8 + h;
  const int wm = wave & 1, wn = wave >> 1;

  f32x4 zero = {0.f, 0.f, 0.f, 0.f};
  f32x4 acc[4][4];
#pragma unroll
  for (int i = 0; i < 4; i++)
#pragma unroll
    for (int j = 0; j < 4; j++) acc[i][j] = zero;

  // phase 1: q = xn @ WqT[head rows]
  for (int k0 = 0; k0 < 1024; k0 += 32) {
    __syncthreads();
    stage128x32(g_xn + (size_t)m0 * 1024 + k0, 1024, As, wave, lane);
    stage128x32(g_WT[0] + (size_t)(h * 128) * 1024 + k0, 1024, Bs, wave, lane);
    __syncthreads();
    bf16x8 af[4], bfr[4];
#pragma unroll
    for (int i = 0; i < 4; i++) af[i] = frag_ld(As, wm * 64 + i * 16 + (lane & 15), lane);
#pragma unroll
    for (int j = 0; j < 4; j++) bfr[j] = frag_ld(Bs, wn * 64 + j * 16 + (lane & 15), lane);
#pragma unroll
    for (int i = 0; i < 4; i++)
#pragma unroll
      for (int j = 0; j < 4; j++)
        acc[i][j] = __builtin_amdgcn_mfma_f32_16x16x32_bf16(af[i], bfr[j], acc[i][j], 0, 0, 0);
  }

  // epilogue 1: exp (clamped), store to qs, row-sum into zqp
#pragma unroll
  for (int i = 0; i < 4; i++)
#pragma unroll
    for (int r = 0; r < 4; r++) {
      const int rowl = wm * 64 + i * 16 + (lane >> 4) * 4 + r;
      float rs = 0.f;
#pragma unroll
      for (int j = 0; j < 4; j++) {
        const int coll = wn * 64 + j * 16 + (lane & 15);
        const float e = __expf(fminf(acc[i][j][r] + bq[h * 128 + coll], 30.0f));
        qs[rowl * 136 + coll] = f2b(e);
        rs += e;
      }
      rs += __shfl_xor(rs, 1);
      rs += __shfl_xor(rs, 2);
      rs += __shfl_xor(rs, 4);
      rs += __shfl_xor(rs, 8);
      if ((lane & 15) == 0) zqp[wn][rowl] = rs;
    }
  __syncthreads();

  // phase 2: y = qs @ attT[bh]^T  (K = 128)
  f32x4 acc2[4][4];
#pragma unroll
  for (int i = 0; i < 4; i++)
#pragma unroll
    for (int j = 0; j < 4; j++) acc2[i][j] = zero;

  for (int k0 = 0; k0 < 128; k0 += 32) {
    __syncthreads();
    stage128x32(g_attT + (size_t)bh * 16384 + k0, 128, Bs, wave, lane);
    __syncthreads();
    bf16x8 af[4], bfr[4];
#pragma unroll
    for (int i = 0; i < 4; i++)
      af[i] = *(const bf16x8*)&qs[(wm * 64 + i * 16 + (lane & 15)) * 136 + k0 + (lane >> 4) * 8];
#pragma unroll
    for (int j = 0; j < 4; j++) bfr[j] = frag_ld(Bs, wn * 64 + j * 16 + (lane & 15), lane);
#pragma unroll
    for (int i = 0; i < 4; i++)
#pragma unroll
      for (int j = 0; j < 4; j++)
        acc2[i][j] = __builtin_amdgcn_mfma_f32_16x16x32_bf16(af[i], bfr[j], acc2[i][j], 0, 0, 0);
  }

  // epilogue 2: out = x + y / Zq  (fp32)
#pragma unroll
  for (int i = 0; i < 4; i++)
#pragma unroll
    for (int r = 0; r < 4; r++) {
      const int rowl = wm * 64 + i * 16 + (lane >> 4) * 4 + r;
      const float zq = fmaxf(zqp[0][rowl] + zqp[1][rowl], 1e-30f);
      const size_t n = (size_t)m0 + rowl;
#pragma unroll
      for (int j = 0; j < 4; j++) {
        const int coll = wn * 64 + j * 16 + (lane & 15);
        const size_t idx = n * 1024 + h * 128 + coll;
        out[idx] = x[idx] + acc2[i][j][r] / zq;
      }
    }
}

// ----------------------------------------------------------------- launch
extern "C" void kernel_launch(void* const* d_in, const int* in_sizes, int n_in,
                              void* d_out, int out_size, void* d_ws, size_t ws_size,
                              hipStream_t stream) {
  const float* x = (const float*)d_in[0];
  const float* mask = (const float*)d_in[1];
  const float* Wq = (const float*)d_in[2];
  const float* bq = (const float*)d_in[3];
  const float* Wk = (const float*)d_in[4];
  const float* bk = (const float*)d_in[5];
  const float* Wv = (const float*)d_in[6];
  const float* bv = (const float*)d_in[7];
  const float* gamma = (const float*)d_in[8];
  const float* beta = (const float*)d_in[9];
  float* out = (float*)d_out;
  (void)d_ws; (void)ws_size;

  transpose_kernel<<<dim3(32, 32, 3), 256, 0, stream>>>(Wq, Wk, Wv);
  ln_kernel<<<dim3(16384), 256, 0, stream>>>(x, gamma, beta);
  gemm_kv<<<dim3(8, 128, 2), 256, 0, stream>>>(bk, bv, mask);
  zrow_kernel<<<dim3(256, 4), 256, 0, stream>>>();
  gemm_att<<<dim3(16, 32), 256, 0, stream>>>();
  attnorm_kernel<<<dim3(32, 8), 256, 0, stream>>>();
  gemm_qy<<<dim3(8, 128), 256, 0, stream>>>(bq, x, out);
}

// Round 6
// 380.775 us; speedup vs baseline: 1.1129x; 1.0573x over previous
//
#include <hip/hip_runtime.h>
#include <stdint.h>

// EfficientSelfAttention on MI355X (gfx950). External I/O FP32; internals bf16
// MFMA. B=4, T=4096, D=1024, H=8, Dh=128. Scratch in __device__ globals.
// R6: XCD-aware swizzle for gemm_kv / gemm_qy — blocks sharing an xn A-slab
// (same m0) land on one XCD so its L2 serves re-reads (FETCH 285->~100MB).
// Occupancy is register-capped (76 VGPR + 64 AGPR -> 3 waves/SIMD), so we
// attack stall latency, not wave count.

typedef unsigned short u16;
typedef __attribute__((ext_vector_type(8))) short bf16x8;
typedef __attribute__((ext_vector_type(4))) float f32x4;

// ------------------------------------------------------- device workspace
__device__ u16 g_WT[3][1024 * 1024];   // 6 MiB: WqT, WkT, WvT (bf16)
__device__ u16 g_xn[16777216];         // 32 MiB
__device__ u16 g_ekT[16777216];        // 32 MiB  [b][d][t]
__device__ u16 g_vvT[16777216];        // 32 MiB  [b][l][t]
__device__ float g_attp[8388608];      // 32 MiB  [kc*32+bh][d*128+l], 16 chunks
__device__ u16 g_attT[524288];         // 1 MiB   [bh][l*128+d]
__device__ float g_Z[4096];            //         [b*1024+d]

__device__ __forceinline__ float b2f(u16 u) {
  union { unsigned int i; float f; } c;
  c.i = ((unsigned int)u) << 16;
  return c.f;
}
__device__ __forceinline__ u16 f2b(float f) {
  union { float f; unsigned int i; } c;
  c.f = f;
  unsigned int r = c.i + 0x7fffu + ((c.i >> 16) & 1u);
  return (u16)(r >> 16);
}

__device__ __forceinline__ void gload16(const void* g, void* l) {
  __builtin_amdgcn_global_load_lds(
      reinterpret_cast<const __attribute__((address_space(1))) uint32_t*>(
          reinterpret_cast<uintptr_t>(g)),
      reinterpret_cast<__attribute__((address_space(3))) uint32_t*>(
          reinterpret_cast<uintptr_t>(l)),
      16, 0, 0);
}

// Stage 128x32 bf16 tile (row stride `stride` elems) into 8KB LDS [128][32].
__device__ __forceinline__ void stage128x32(const u16* g, int stride, char* lds,
                                            int wave, int lane) {
  const int r = wave * 32 + (lane >> 2);
  const int cb = (lane & 3) * 16;
  const char* gp = (const char*)g;
  gload16(gp + (size_t)r * stride * 2 + cb, lds + wave * 2048);
  gload16(gp + (size_t)(r + 16) * stride * 2 + cb, lds + wave * 2048 + 1024);
}

// A/B fragment from [128][32] LDS tile: row `row`, k = (lane>>4)*8 .. +7
__device__ __forceinline__ bf16x8 frag_ld(const char* lds, int row, int lane) {
  return *(const bf16x8*)(lds + row * 64 + ((lane >> 4) * 16));
}

// ---------------------------------------------------------------- LayerNorm
__global__ __launch_bounds__(256) void ln_kernel(const float* __restrict__ x,
                                                 const float* __restrict__ gamma,
                                                 const float* __restrict__ beta) {
  const int row = blockIdx.x;
  const int tid = threadIdx.x;
  const int wave = tid >> 6, lane = tid & 63;
  const float* xr = x + (size_t)row * 1024;
  float4 u = ((const float4*)xr)[tid];
  float v0 = u.x, v1 = u.y, v2 = u.z, v3 = u.w;
  float s = v0 + v1 + v2 + v3;
  float s2 = v0 * v0 + v1 * v1 + v2 * v2 + v3 * v3;
#pragma unroll
  for (int off = 32; off > 0; off >>= 1) {
    s += __shfl_down(s, off);
    s2 += __shfl_down(s2, off);
  }
  __shared__ float ls[4], ls2[4];
  if (lane == 0) { ls[wave] = s; ls2[wave] = s2; }
  __syncthreads();
  s = ls[0] + ls[1] + ls[2] + ls[3];
  s2 = ls2[0] + ls2[1] + ls2[2] + ls2[3];
  const float mu = s * (1.0f / 1024.0f);
  const float var = fmaxf(s2 * (1.0f / 1024.0f) - mu * mu, 0.0f);
  const float rstd = rsqrtf(var + 1e-5f);
  float4 g4 = ((const float4*)gamma)[tid];
  float4 be = ((const float4*)beta)[tid];
  ushort4 o;
  o.x = f2b((v0 - mu) * rstd * g4.x + be.x);
  o.y = f2b((v1 - mu) * rstd * g4.y + be.y);
  o.z = f2b((v2 - mu) * rstd * g4.z + be.z);
  o.w = f2b((v3 - mu) * rstd * g4.w + be.w);
  *(ushort4*)(g_xn + (size_t)row * 1024 + tid * 4) = o;
}

// -------------------- weight transpose+cast (1Kx1K, fp32->bf16), z = which W
__global__ __launch_bounds__(256) void transpose_kernel(const float* __restrict__ wq,
                                                        const float* __restrict__ wk,
                                                        const float* __restrict__ wv) {
  __shared__ u16 tile[32][33];
  const int which = blockIdx.z;
  const float* src = (which == 0) ? wq : (which == 1) ? wk : wv;
  u16* dst = g_WT[which];
  const int tx = threadIdx.x & 31;
  const int ty = threadIdx.x >> 5;
  const int c0 = blockIdx.x * 32, r0 = blockIdx.y * 32;
#pragma unroll
  for (int i = 0; i < 4; i++)
    tile[ty + i * 8][tx] = f2b(src[(size_t)(r0 + ty + i * 8) * 1024 + c0 + tx]);
  __syncthreads();
#pragma unroll
  for (int i = 0; i < 4; i++)
    dst[(size_t)(c0 + ty + i * 8) * 1024 + r0 + tx] = tile[tx][ty + i * 8];
}

// --------------------------------------------------------------- K/V GEMM
// z=0: ekT[b][d][t] = (m>0.5) ? exp(xn@Wk^T + bk) : 0
// z=1: vvT[b][l][t] = (xn@Wv^T + bv) * m
// 1-D grid 2048, XCD swizzle: c=L&7 owns m0 = c+8*(L>>7); (n0,z) = (L>>3)&15.
__global__ __launch_bounds__(256) void gemm_kv(const float* __restrict__ bk,
                                               const float* __restrict__ bv,
                                               const float* __restrict__ mask) {
  __shared__ __align__(16) char smem[34816];
  char* As = smem;
  char* Bs = smem + 8192;
  u16* tT = (u16*)smem;  // [feature][token] 128x136, written AFTER K-loop
  const int tid = threadIdx.x, wave = tid >> 6, lane = tid & 63;
  const int L = blockIdx.x;
  const int c = L & 7;           // XCD (heuristic: round-robin dispatch)
  const int k = L >> 3;          // 0..255
  const int inner = k & 15;      // 16 blocks sharing one m0 slab
  const int n0 = (inner & 7) * 128;
  const int z = inner >> 3;
  const int m0 = (c + 8 * (k >> 4)) * 128;  // token block, m0%8 == XCD
  const u16* wt = z ? g_WT[2] : g_WT[1];
  const float* bias = z ? bv : bk;
  u16* outT = z ? g_vvT : g_ekT;
  const int b = m0 >> 12;
  const int t0 = m0 & 4095;
  const int wm = wave & 1, wn = wave >> 1;

  f32x4 zero = {0.f, 0.f, 0.f, 0.f};
  f32x4 acc[4][4];
#pragma unroll
  for (int i = 0; i < 4; i++)
#pragma unroll
    for (int j = 0; j < 4; j++) acc[i][j] = zero;

  for (int k0 = 0; k0 < 1024; k0 += 32) {
    __syncthreads();
    stage128x32(g_xn + (size_t)m0 * 1024 + k0, 1024, As, wave, lane);
    stage128x32(wt + (size_t)n0 * 1024 + k0, 1024, Bs, wave, lane);
    __syncthreads();
    bf16x8 af[4], bfr[4];
#pragma unroll
    for (int i = 0; i < 4; i++) af[i] = frag_ld(As, wm * 64 + i * 16 + (lane & 15), lane);
#pragma unroll
    for (int j = 0; j < 4; j++) bfr[j] = frag_ld(Bs, wn * 64 + j * 16 + (lane & 15), lane);
#pragma unroll
    for (int i = 0; i < 4; i++)
#pragma unroll
      for (int j = 0; j < 4; j++)
        acc[i][j] = __builtin_amdgcn_mfma_f32_16x16x32_bf16(af[i], bfr[j], acc[i][j], 0, 0, 0);
  }
  __syncthreads();  // all waves done reading As/Bs before tT overwrites them

#pragma unroll
  for (int i = 0; i < 4; i++)
#pragma unroll
    for (int r = 0; r < 4; r++) {
      const int rowl = wm * 64 + i * 16 + (lane >> 4) * 4 + r;  // local token
      const float mv = mask[m0 + rowl];
#pragma unroll
      for (int j = 0; j < 4; j++) {
        const int coll = wn * 64 + j * 16 + (lane & 15);  // local feature
        const float a = acc[i][j][r] + bias[n0 + coll];
        float o;
        if (z)
          o = a * mv;
        else
          o = (mv > 0.5f) ? __expf(fminf(a, 30.0f)) : 0.0f;
        tT[coll * 136 + rowl] = f2b(o);
      }
    }
  __syncthreads();
  const size_t gbase = (size_t)b * (1024 * 4096) + (size_t)n0 * 4096 + t0;
#pragma unroll
  for (int u = 0; u < 8; u++) {
    const int v = u * 256 + tid;
    const int cc = v >> 4, rb = (v & 15) * 8;
    uint4 val = *(const uint4*)&tT[cc * 136 + rb];
    *(uint4*)(outT + gbase + (size_t)cc * 4096 + rb) = val;
  }
}

// --------------------------------------------------- Z[b][d] = sum_t ekT
__global__ __launch_bounds__(256) void zrow_kernel() {
  const int tid = threadIdx.x, wave = tid >> 6, lane = tid & 63;
  const int d = blockIdx.x * 4 + wave;
  const int b = blockIdx.y;
  const u16* p = g_ekT + (size_t)b * (1024 * 4096) + (size_t)d * 4096;
  float s = 0.f;
#pragma unroll
  for (int pass = 0; pass < 8; pass++) {
    uint4 w4 = *(const uint4*)(p + pass * 512 + lane * 8);
    unsigned int w[4] = {w4.x, w4.y, w4.z, w4.w};
#pragma unroll
    for (int q = 0; q < 4; q++) {
      s += b2f((u16)(w[q] & 0xffff));
      s += b2f((u16)(w[q] >> 16));
    }
  }
#pragma unroll
  for (int m = 1; m < 64; m <<= 1) s += __shfl_xor(s, m);
  if (lane == 0) g_Z[b * 1024 + d] = s;
}

// ------------------------------------------------------------- att GEMM
// attp[kc][bh][d][l] = sum_{t in 256-chunk kc} ekT[b][h*128+d][t]*vvT[b][h*128+l][t]
__global__ __launch_bounds__(256) void gemm_att() {
  __shared__ __align__(16) char As[8192];
  __shared__ __align__(16) char Bs[8192];
  const int tid = threadIdx.x, wave = tid >> 6, lane = tid & 63;
  const int kc = blockIdx.x;  // 0..15
  const int bh = blockIdx.y;  // 0..31
  const int b = bh >> 3, h = bh & 7;
  const size_t base = (size_t)b * (1024 * 4096) + (size_t)(h * 128) * 4096;
  const int wm = wave & 1, wn = wave >> 1;

  f32x4 zero = {0.f, 0.f, 0.f, 0.f};
  f32x4 acc[4][4];
#pragma unroll
  for (int i = 0; i < 4; i++)
#pragma unroll
    for (int j = 0; j < 4; j++) acc[i][j] = zero;

  for (int kt = 0; kt < 256; kt += 32) {
    const int k0 = kc * 256 + kt;
    __syncthreads();
    stage128x32(g_ekT + base + k0, 4096, As, wave, lane);
    stage128x32(g_vvT + base + k0, 4096, Bs, wave, lane);
    __syncthreads();
    bf16x8 af[4], bfr[4];
#pragma unroll
    for (int i = 0; i < 4; i++) af[i] = frag_ld(As, wm * 64 + i * 16 + (lane & 15), lane);
#pragma unroll
    for (int j = 0; j < 4; j++) bfr[j] = frag_ld(Bs, wn * 64 + j * 16 + (lane & 15), lane);
#pragma unroll
    for (int i = 0; i < 4; i++)
#pragma unroll
      for (int j = 0; j < 4; j++)
        acc[i][j] = __builtin_amdgcn_mfma_f32_16x16x32_bf16(af[i], bfr[j], acc[i][j], 0, 0, 0);
  }

  float* op = g_attp + ((size_t)(kc * 32 + bh)) * 16384;
#pragma unroll
  for (int i = 0; i < 4; i++)
#pragma unroll
    for (int r = 0; r < 4; r++) {
      const int row = wm * 64 + i * 16 + (lane >> 4) * 4 + r;
#pragma unroll
      for (int j = 0; j < 4; j++) {
        const int col = wn * 64 + j * 16 + (lane & 15);
        op[row * 128 + col] = acc[i][j][r];
      }
    }
}

// ------------------------------------- reduce partials, /Z, store attT[bh][l][d]
__global__ __launch_bounds__(256) void attnorm_kernel() {
  const int bh = blockIdx.x;
  const int b = bh >> 3, h = bh & 7;
  const int tid = threadIdx.x;
  __shared__ float Zl[128];
  if (tid < 128) Zl[tid] = fmaxf(g_Z[b * 1024 + h * 128 + tid], 1e-30f);
  __syncthreads();
  const int i0 = blockIdx.y * 2048;
  for (int i = i0 + tid; i < i0 + 2048; i += 256) {
    const int d = i >> 7, l = i & 127;
    float s = 0.f;
#pragma unroll
    for (int c = 0; c < 16; c++) s += g_attp[((size_t)(c * 32 + bh)) * 16384 + i];
    g_attT[(size_t)bh * 16384 + l * 128 + d] = f2b(s / Zl[d]);
  }
}

// ---------------------------------------------------------- fused q + y
// 1-D grid 1024, XCD swizzle: c=L&7, k=L>>3; m0 = c+8*(k>>3); h = k&7.
__global__ __launch_bounds__(256) void gemm_qy(const float* __restrict__ bq,
                                               const float* __restrict__ x,
                                               float* __restrict__ out) {
  __shared__ __align__(16) char As[8192];
  __shared__ __align__(16) char Bs[8192];
  __shared__ __align__(16) u16 qs[128 * 136];  // [token][feature] padded
  __shared__ float zqp[2][128];
  const int tid = threadIdx.x, wave = tid >> 6, lane = tid & 63;
  const int L = blockIdx.x;
  const int c = L & 7;
  const int k = L >> 3;              // 0..127
  const int h = k & 7;               // head
  const int m0 = (c + 8 * (k >> 3)) * 128;  // token block, m0%8 == XCD
  const int b = m0 >> 12;
  const int bh = b * 8 + h;
  const int wm = wave & 1, wn = wave >> 1;

  f32x4 zero = {0.f, 0.f, 0.f, 0.f};
  f32x4 acc[4][4];
#pragma unroll
  for (int i = 0; i < 4; i++)
#pragma unroll
    for (int j = 0; j < 4; j++) acc[i][j] = zero;

  // phase 1: q = xn @ WqT[head rows]
  for (int k0 = 0; k0 < 1024; k0 += 32) {
    __syncthreads();
    stage128x32(g_xn + (size_t)m0 * 1024 + k0, 1024, As, wave, lane);
    stage128x32(g_WT[0] + (size_t)(h * 128) * 1024 + k0, 1024, Bs, wave, lane);
    __syncthreads();
    bf16x8 af[4], bfr[4];
#pragma unroll
    for (int i = 0; i < 4; i++) af[i] = frag_ld(As, wm * 64 + i * 16 + (lane & 15), lane);
#pragma unroll
    for (int j = 0; j < 4; j++) bfr[j] = frag_ld(Bs, wn * 64 + j * 16 + (lane & 15), lane);
#pragma unroll
    for (int i = 0; i < 4; i++)
#pragma unroll
      for (int j = 0; j < 4; j++)
        acc[i][j] = __builtin_amdgcn_mfma_f32_16x16x32_bf16(af[i], bfr[j], acc[i][j], 0, 0, 0);
  }

  // epilogue 1: exp (clamped), store to qs, row-sum into zqp
#pragma unroll
  for (int i = 0; i < 4; i++)
#pragma unroll
    for (int r = 0; r < 4; r++) {
      const int rowl = wm * 64 + i * 16 + (lane >> 4) * 4 + r;
      float rs = 0.f;
#pragma unroll
      for (int j = 0; j < 4; j++) {
        const int coll = wn * 64 + j * 16 + (lane & 15);
        const float e = __expf(fminf(acc[i][j][r] + bq[h * 128 + coll], 30.0f));
        qs[rowl * 136 + coll] = f2b(e);
        rs += e;
      }
      rs += __shfl_xor(rs, 1);
      rs += __shfl_xor(rs, 2);
      rs += __shfl_xor(rs, 4);
      rs += __shfl_xor(rs, 8);
      if ((lane & 15) == 0) zqp[wn][rowl] = rs;
    }
  __syncthreads();

  // phase 2: y = qs @ attT[bh]^T  (K = 128)
  f32x4 acc2[4][4];
#pragma unroll
  for (int i = 0; i < 4; i++)
#pragma unroll
    for (int j = 0; j < 4; j++) acc2[i][j] = zero;

  for (int k0 = 0; k0 < 128; k0 += 32) {
    __syncthreads();
    stage128x32(g_attT + (size_t)bh * 16384 + k0, 128, Bs, wave, lane);
    __syncthreads();
    bf16x8 af[4], bfr[4];
#pragma unroll
    for (int i = 0; i < 4; i++)
      af[i] = *(const bf16x8*)&qs[(wm * 64 + i * 16 + (lane & 15)) * 136 + k0 + (lane >> 4) * 8];
#pragma unroll
    for (int j = 0; j < 4; j++) bfr[j] = frag_ld(Bs, wn * 64 + j * 16 + (lane & 15), lane);
#pragma unroll
    for (int i = 0; i < 4; i++)
#pragma unroll
      for (int j = 0; j < 4; j++)
        acc2[i][j] = __builtin_amdgcn_mfma_f32_16x16x32_bf16(af[i], bfr[j], acc2[i][j], 0, 0, 0);
  }

  // epilogue 2: out = x + y / Zq  (fp32)
#pragma unroll
  for (int i = 0; i < 4; i++)
#pragma unroll
    for (int r = 0; r < 4; r++) {
      const int rowl = wm * 64 + i * 16 + (lane >> 4) * 4 + r;
      const float zq = fmaxf(zqp[0][rowl] + zqp[1][rowl], 1e-30f);
      const size_t n = (size_t)m0 + rowl;
#pragma unroll
      for (int j = 0; j < 4; j++) {
        const int coll = wn * 64 + j * 16 + (lane & 15);
        const size_t idx = n * 1024 + h * 128 + coll;
        out[idx] = x[idx] + acc2[i][j][r] / zq;
      }
    }
}

// ----------------------------------------------------------------- launch
extern "C" void kernel_launch(void* const* d_in, const int* in_sizes, int n_in,
                              void* d_out, int out_size, void* d_ws, size_t ws_size,
                              hipStream_t stream) {
  const float* x = (const float*)d_in[0];
  const float* mask = (const float*)d_in[1];
  const float* Wq = (const float*)d_in[2];
  const float* bq = (const float*)d_in[3];
  const float* Wk = (const float*)d_in[4];
  const float* bk = (const float*)d_in[5];
  const float* Wv = (const float*)d_in[6];
  const float* bv = (const float*)d_in[7];
  const float* gamma = (const float*)d_in[8];
  const float* beta = (const float*)d_in[9];
  float* out = (float*)d_out;
  (void)d_ws; (void)ws_size;

  transpose_kernel<<<dim3(32, 32, 3), 256, 0, stream>>>(Wq, Wk, Wv);
  ln_kernel<<<dim3(16384), 256, 0, stream>>>(x, gamma, beta);
  gemm_kv<<<dim3(2048), 256, 0, stream>>>(bk, bv, mask);
  zrow_kernel<<<dim3(256, 4), 256, 0, stream>>>();
  gemm_att<<<dim3(16, 32), 256, 0, stream>>>();
  attnorm_kernel<<<dim3(32, 8), 256, 0, stream>>>();
  gemm_qy<<<dim3(1024), 256, 0, stream>>>(bq, x, out);
}